// Round 2
// baseline (191.895 us; speedup 1.0000x reference)
//
#include <hip/hip_runtime.h>
#include <hip/hip_bf16.h>
#include <stdint.h>

#define M_DIM 4096
#define N_DIM 4096
#define K_DIM 2048

typedef __bf16 bf16x8 __attribute__((ext_vector_type(8)));
typedef float f32x4 __attribute__((ext_vector_type(4)));
typedef unsigned short u16x8 __attribute__((ext_vector_type(8)));

// ---------------- fp32 -> bf16 (RNE) ----------------
__device__ __forceinline__ unsigned short f32_to_bf16(float f) {
  union { float f; unsigned int u; } c; c.f = f;
  unsigned int u = c.u;
  unsigned int r = (u + 0x7FFFu + ((u >> 16) & 1u)) >> 16;
  return (unsigned short)r;
}

// Convert BOTH tensors fp32->bf16 with the XOR column-granule swizzle
// (granule g of row r within each 64-col K-tile holds source granule
// g ^ (r&7)) so the forced-linear global_load_lds staging yields a
// bank-conflict-free LDS tile. Block 0 additionally zeroes S.
__global__ void __launch_bounds__(256) cvt_swz_kernel(
    const float* __restrict__ x, const float* __restrict__ w,
    unsigned short* __restrict__ xb, unsigned short* __restrict__ wb,
    float* __restrict__ S) {
  if (blockIdx.x == 0) {
#pragma unroll
    for (int k = 0; k < 16; ++k)
      S[threadIdx.x + k * 256] = 0.f;
  }

  const int nG = M_DIM * K_DIM / 8;  // granules per tensor
  int i = blockIdx.x * 256 + threadIdx.x;
  const float* src;
  unsigned short* dst;
  int gid;
  if (i < nG) { src = x; dst = xb; gid = i; }
  else        { src = w; dst = wb; gid = i - nG; }

  const int row = gid >> 8;        // K/8 = 256 granules per row
  const int cg  = gid & 255;
  const int kt  = cg >> 3;
  const int g   = cg & 7;
  const int sg  = g ^ (row & 7);   // swizzled source granule

  const float4* s4 = (const float4*)(src + (size_t)row * K_DIM + kt * 64 + sg * 8);
  float4 f0 = s4[0], f1 = s4[1];
  u16x8 o;
  o[0] = f32_to_bf16(f0.x); o[1] = f32_to_bf16(f0.y);
  o[2] = f32_to_bf16(f0.z); o[3] = f32_to_bf16(f0.w);
  o[4] = f32_to_bf16(f1.x); o[5] = f32_to_bf16(f1.y);
  o[6] = f32_to_bf16(f1.z); o[7] = f32_to_bf16(f1.w);
  ((u16x8*)dst)[gid] = o;
}

// ---------------- async global -> LDS, 16B per lane ----------------
__device__ __forceinline__ void gload_lds16(const unsigned short* g, unsigned short* l) {
  __builtin_amdgcn_global_load_lds(
      (const __attribute__((address_space(1))) unsigned int*)g,
      (__attribute__((address_space(3))) unsigned int*)l,
      16, 0, 0);
}

// Stage one 256x64 A-tile + 256x64 B-tile (4 calls each; 512 lanes x 16B
// = 64 rows per call). xg/wg/lA/lB already carry the per-thread offset
// (row tid>>3, col (tid&7)*8  ->  LDS addr = base + tid*16B, the linear
// map global_load_lds requires).
__device__ __forceinline__ void stage_tile(
    const unsigned short* xg, const unsigned short* wg,
    unsigned short* lA, unsigned short* lB, int k0) {
#pragma unroll
  for (int c = 0; c < 4; ++c) {
    gload_lds16(xg + (size_t)(c * 64) * K_DIM + k0, lA + c * 64 * 64);
    gload_lds16(wg + (size_t)(c * 64) * K_DIM + k0, lB + c * 64 * 64);
  }
}

// One K=64 compute step on a staged tile pair.
// R1 CHANGE vs the 58.6us R6 baseline: issue ALL 24 ds_read_b128 up front
// (both K-slices), pin the issue order with sched_barrier(0), THEN run the
// 64 MFMAs. R6's per-ks order (12 reads, 32 MFMA, 12 reads, 32 MFMA) made
// all 8 waves ping-pong LDS-phase/MFMA-phase in lockstep from the common
// barrier -> 2304cy LDS + 2483cy MFMA per tile fully SERIALIZED (= measured
// 58.6us). With reads hoisted, the compiler's fine-grained lgkmcnt waits
// only for the ks=0 frags before the first MFMA, and the LDS unit serves
// the ks=1 reads UNDER the ks=0 MFMA cluster. Cost: 24 frags live = +96
// operand VGPRs (acc is in AGPRs); still >=2 waves/SIMD.
__device__ __forceinline__ void compute_tile(
    const unsigned short* As, const unsigned short* Bs,
    int wr, int wc, int lr, int q, f32x4 acc[4][8]) {
  bf16x8 af[2][4], bfr[2][8];
#pragma unroll
  for (int ks = 0; ks < 2; ++ks) {
    // granule G = ks*4 + q; swizzled col = (G ^ (lr&7)) * 8
    const int swcol = ((ks * 4 + q) ^ (lr & 7)) * 8;
#pragma unroll
    for (int i = 0; i < 4; ++i)
      af[ks][i]  = *(const bf16x8*)(As + (wr + i * 16 + lr) * 64 + swcol);
#pragma unroll
    for (int i = 0; i < 8; ++i)
      bfr[ks][i] = *(const bf16x8*)(Bs + (wc + i * 16 + lr) * 64 + swcol);
  }
  // Keep all 24 read issues ahead of the MFMA cluster (stop the scheduler
  // from sinking the ks=1 reads below the ks=0 MFMAs under pressure).
  __builtin_amdgcn_sched_barrier(0);
#pragma unroll
  for (int ks = 0; ks < 2; ++ks)
#pragma unroll
    for (int mi = 0; mi < 4; ++mi)
#pragma unroll
      for (int ni = 0; ni < 8; ++ni)
        acc[mi][ni] = __builtin_amdgcn_mfma_f32_16x16x32_bf16(
            af[ks][mi], bfr[ks][ni], acc[mi][ni], 0, 0, 0);
}

// ---------------- fused GEMM -> clamp -> sum exp(v-10) per row ----------------
// 256x256 block tile, 512 threads = 8 waves, each wave 64x128 (4x8 frags of
// 16x16x32 bf16). DOUBLE-BUFFERED LDS (128 KB dynamic), ONE barrier per
// K-tile: DMA for tile kt+1 issues right after the barrier and stays in
// flight across the whole compute(kt) phase, so the barrier's vmcnt(0)
// drain is ~free; ds_read/MFMA overlap comes from the hoisted reads in
// compute_tile.
__global__ void __launch_bounds__(512, 2) gemm_lse_kernel(
    const unsigned short* __restrict__ xb,   // [M][K] bf16, swizzled granules
    const unsigned short* __restrict__ wb,   // [N][K] bf16, swizzled granules
    const float* __restrict__ bias,          // [N]
    float* __restrict__ S) {                 // [M] partial sums of exp(clamp(v)-10)
  extern __shared__ __align__(16) unsigned short lds[];
  unsigned short* As0 = lds;                  // 256*64 shorts = 32 KB
  unsigned short* As1 = lds + 16384;
  unsigned short* Bs0 = lds + 32768;
  unsigned short* Bs1 = lds + 49152;

  const int tid = threadIdx.x;
  const int bm0 = blockIdx.y * 256;
  const int bn0 = blockIdx.x * 256;

  const int wave = tid >> 6, lane = tid & 63;
  const int wr = (wave & 3) * 64;    // wave row offset (0..192)
  const int wc = (wave >> 2) * 128;  // wave col offset (0/128)
  const int lr = lane & 15;
  const int q  = lane >> 4;

  f32x4 acc[4][8];
  const f32x4 zero = {0.f, 0.f, 0.f, 0.f};
#pragma unroll
  for (int mi = 0; mi < 4; ++mi)
#pragma unroll
    for (int ni = 0; ni < 8; ++ni)
      acc[mi][ni] = zero;

  const int srow = tid >> 3;        // 0..63
  const int scol = (tid & 7) * 8;

  const unsigned short* xg = xb + (size_t)(bm0 + srow) * K_DIM + scol;
  const unsigned short* wg = wb + (size_t)(bn0 + srow) * K_DIM + scol;
  unsigned short* lA = lds + tid * 8;            // into As0 (+16384 for As1)
  unsigned short* lB = lds + 32768 + tid * 8;    // into Bs0 (+16384 for Bs1)

  stage_tile(xg, wg, lA, lB, 0);                 // prologue: tile 0 -> buf0

  for (int kt = 0; kt < 32; kt += 2) {
    __syncthreads();  // drains this wave's DMA (tile kt, issued a full
                      // compute-phase ago) + syncs: buf1 free to overwrite
    if (kt + 1 < 32)
      stage_tile(xg, wg, lA + 16384, lB + 16384, (kt + 1) * 64);
    compute_tile(As0, Bs0, wr, wc, lr, q, acc);

    __syncthreads();  // drains tile kt+1 DMA; buf0 free to overwrite
    if (kt + 2 < 32)
      stage_tile(xg, wg, lA, lB, (kt + 2) * 64);
    compute_tile(As1, Bs1, wr, wc, lr, q, acc);
  }

  // Epilogue: bias + clamp + exp(v-10); reduce across 16 lanes (128 cols);
  // one fire-and-forget atomic per row per wave (32 contributions/row total).
  float bv[8];
#pragma unroll
  for (int ni = 0; ni < 8; ++ni)
    bv[ni] = bias[bn0 + wc + ni * 16 + lr];

#pragma unroll
  for (int mi = 0; mi < 4; ++mi) {
#pragma unroll
    for (int reg = 0; reg < 4; ++reg) {
      float s = 0.f;
#pragma unroll
      for (int ni = 0; ni < 8; ++ni) {
        float v = acc[mi][ni][reg] + bv[ni];  // SCALE_FACTOR*2 == 1.0
        v = fminf(fmaxf(v, -10.f), 10.f);
        s += __expf(v - 10.f);
      }
      s += __shfl_xor(s, 1);
      s += __shfl_xor(s, 2);
      s += __shfl_xor(s, 4);
      s += __shfl_xor(s, 8);
      if (lr == 0)
        atomicAdd(&S[bm0 + wr + mi * 16 + q * 4 + reg], s);
    }
  }
}

// ---------------- finalize: lse = 10 + log(S); mish(lse) ----------------
__global__ void __launch_bounds__(256) finalize_kernel(const float* __restrict__ S,
                                                       float* __restrict__ out) {
  int i = blockIdx.x * blockDim.x + threadIdx.x;
  float lse = 10.0f + logf(S[i]);
  float sp = fmaxf(lse, 0.f) + log1pf(expf(-fabsf(lse)));  // stable softplus
  out[i] = lse * tanhf(sp);
}

extern "C" void kernel_launch(void* const* d_in, const int* in_sizes, int n_in,
                              void* d_out, int out_size, void* d_ws, size_t ws_size,
                              hipStream_t stream) {
  const float* x = (const float*)d_in[0];   // [4096, 2048]
  const float* W = (const float*)d_in[1];   // [4096, 2048]
  const float* b = (const float*)d_in[2];   // [4096]
  float* out = (float*)d_out;               // [4096]

  char* ws = (char*)d_ws;
  float* S = (float*)ws;                                       // 16 KB
  unsigned short* xb = (unsigned short*)(ws + 16384);          // 16 MB
  unsigned short* wb = (unsigned short*)(ws + 16384 + (size_t)M_DIM * K_DIM * 2);

  const int nG2 = 2 * M_DIM * K_DIM / 8;  // both tensors, 16B granules
  cvt_swz_kernel<<<nG2 / 256, 256, 0, stream>>>(x, W, xb, wb, S);

  // 128 KB dynamic LDS needs the opt-in attribute (idempotent, capture-safe).
  hipFuncSetAttribute((const void*)gemm_lse_kernel,
                      hipFuncAttributeMaxDynamicSharedMemorySize, 131072);
  dim3 grid(N_DIM / 256, M_DIM / 256);  // 16 x 16 = 256 blocks, 1/CU
  gemm_lse_kernel<<<grid, 512, 131072, stream>>>(xb, wb, b, S);

  finalize_kernel<<<M_DIM / 256, 256, 0, stream>>>(S, out);
}

// Round 3
// 154.371 us; speedup vs baseline: 1.2431x; 1.2431x over previous
//
#include <hip/hip_runtime.h>
#include <hip/hip_bf16.h>
#include <stdint.h>

#define M_DIM 4096
#define N_DIM 4096
#define K_DIM 2048

typedef __bf16 bf16x8 __attribute__((ext_vector_type(8)));
typedef float f32x4 __attribute__((ext_vector_type(4)));
typedef unsigned short u16x8 __attribute__((ext_vector_type(8)));

// ---------------- fp32 -> bf16 (RNE) ----------------
__device__ __forceinline__ unsigned short f32_to_bf16(float f) {
  union { float f; unsigned int u; } c; c.f = f;
  unsigned int u = c.u;
  unsigned int r = (u + 0x7FFFu + ((u >> 16) & 1u)) >> 16;
  return (unsigned short)r;
}

// Convert BOTH tensors fp32->bf16 with the XOR column-granule swizzle
// (granule g of row r within each 64-col K-tile holds source granule
// g ^ (r&7)) so the forced-linear global_load_lds staging yields a
// bank-conflict-free LDS tile. Block 0 additionally zeroes S.
__global__ void __launch_bounds__(256) cvt_swz_kernel(
    const float* __restrict__ x, const float* __restrict__ w,
    unsigned short* __restrict__ xb, unsigned short* __restrict__ wb,
    float* __restrict__ S) {
  if (blockIdx.x == 0) {
#pragma unroll
    for (int k = 0; k < 16; ++k)
      S[threadIdx.x + k * 256] = 0.f;
  }

  const int nG = M_DIM * K_DIM / 8;  // granules per tensor
  int i = blockIdx.x * 256 + threadIdx.x;
  const float* src;
  unsigned short* dst;
  int gid;
  if (i < nG) { src = x; dst = xb; gid = i; }
  else        { src = w; dst = wb; gid = i - nG; }

  const int row = gid >> 8;        // K/8 = 256 granules per row
  const int cg  = gid & 255;
  const int kt  = cg >> 3;
  const int g   = cg & 7;
  const int sg  = g ^ (row & 7);   // swizzled source granule

  const float4* s4 = (const float4*)(src + (size_t)row * K_DIM + kt * 64 + sg * 8);
  float4 f0 = s4[0], f1 = s4[1];
  u16x8 o;
  o[0] = f32_to_bf16(f0.x); o[1] = f32_to_bf16(f0.y);
  o[2] = f32_to_bf16(f0.z); o[3] = f32_to_bf16(f0.w);
  o[4] = f32_to_bf16(f1.x); o[5] = f32_to_bf16(f1.y);
  o[6] = f32_to_bf16(f1.z); o[7] = f32_to_bf16(f1.w);
  ((u16x8*)dst)[gid] = o;
}

// ---------------- async global -> LDS, 16B per lane ----------------
__device__ __forceinline__ void gload_lds16(const unsigned short* g, unsigned short* l) {
  __builtin_amdgcn_global_load_lds(
      (const __attribute__((address_space(1))) unsigned int*)g,
      (__attribute__((address_space(3))) unsigned int*)l,
      16, 0, 0);
}

// Stage one 256x64 A-tile + 256x64 B-tile (4 calls each; 512 lanes x 16B
// = 64 rows per call). xg/wg/lA/lB already carry the per-thread offset
// (row tid>>3, col (tid&7)*8  ->  LDS addr = base + tid*16B, the linear
// map global_load_lds requires).
__device__ __forceinline__ void stage_tile(
    const unsigned short* xg, const unsigned short* wg,
    unsigned short* lA, unsigned short* lB, int k0) {
#pragma unroll
  for (int c = 0; c < 4; ++c) {
    gload_lds16(xg + (size_t)(c * 64) * K_DIM + k0, lA + c * 64 * 64);
    gload_lds16(wg + (size_t)(c * 64) * K_DIM + k0, lB + c * 64 * 64);
  }
}

// One K=64 compute step on a staged tile pair.
// R3 CHANGE (post-mortem of R1's spill and R0's convoy): fine-grained
// 1-read : 4-MFMA interleave at LOW register pressure.
//   R0 (58.6us): 12-read burst then 32 MFMAs -> all 8 waves' read bursts
//     fair-share the LDS unit post-barrier, every wave's reads finish at
//     ~the same late time, so LDS phase (2304cy) and MFMA phase (2483cy)
//     fully serialize per tile (sum matches 58.6us).
//   R1 (104us): hoisting 24 frags (96 VGPR) blew the 128-VGPR cap
//     (unified RF: 256/wave at 2 waves/SIMD minus 128 acc AGPRs) ->
//     scratch spill, WRITE_SIZE 2MB -> 13MB.
//   Now: per K-slice read 4 A-frags + 2 B-frags, then per ni: prefetch
//     B-frag ni+2, sched_barrier(0) to pin the interleave, 4 MFMAs.
//     Live set ~7 frags (28 VGPR) -- less than R0. Per-wave issue stream
//     becomes load,MFMA,MFMA,MFMA,MFMA,load,... so the LDS pipe runs
//     UNDER the matrix pipe instead of phase-locking with it.
__device__ __forceinline__ void compute_tile(
    const unsigned short* As, const unsigned short* Bs,
    int wr, int wc, int lr, int q, f32x4 acc[4][8]) {
#pragma unroll
  for (int ks = 0; ks < 2; ++ks) {
    // granule G = ks*4 + q; swizzled col = (G ^ (lr&7)) * 8
    const int swcol = ((ks * 4 + q) ^ (lr & 7)) * 8;
    bf16x8 af[4];
#pragma unroll
    for (int i = 0; i < 4; ++i)
      af[i] = *(const bf16x8*)(As + (wr + i * 16 + lr) * 64 + swcol);
    bf16x8 bfr[8];
    bfr[0] = *(const bf16x8*)(Bs + (wc + 0 * 16 + lr) * 64 + swcol);
    bfr[1] = *(const bf16x8*)(Bs + (wc + 1 * 16 + lr) * 64 + swcol);
#pragma unroll
    for (int ni = 0; ni < 8; ++ni) {
      if (ni + 2 < 8)
        bfr[ni + 2] =
            *(const bf16x8*)(Bs + (wc + (ni + 2) * 16 + lr) * 64 + swcol);
      // Pin the interleave: the prefetch read above may not sink below
      // this point; the MFMAs below may not hoist above it. The compiler
      // still inserts the correct fine-grained lgkmcnt for bfr[ni]
      // (2 reads outstanding -> lgkmcnt(2), non-blocking for the ring).
      __builtin_amdgcn_sched_barrier(0);
#pragma unroll
      for (int mi = 0; mi < 4; ++mi)
        acc[mi][ni] = __builtin_amdgcn_mfma_f32_16x16x32_bf16(
            af[mi], bfr[ni], acc[mi][ni], 0, 0, 0);
    }
  }
}

// ---------------- fused GEMM -> clamp -> sum exp(v-10) per row ----------------
// 256x256 block tile, 512 threads = 8 waves, each wave 64x128 (4x8 frags of
// 16x16x32 bf16). DOUBLE-BUFFERED LDS (128 KB dynamic), ONE barrier per
// K-tile: DMA for tile kt+1 issues right after the barrier and stays in
// flight across the whole compute(kt) phase, so the barrier's vmcnt(0)
// drain is ~free; ds_read/MFMA overlap comes from the interleave in
// compute_tile.
__global__ void __launch_bounds__(512, 2) gemm_lse_kernel(
    const unsigned short* __restrict__ xb,   // [M][K] bf16, swizzled granules
    const unsigned short* __restrict__ wb,   // [N][K] bf16, swizzled granules
    const float* __restrict__ bias,          // [N]
    float* __restrict__ S) {                 // [M] partial sums of exp(clamp(v)-10)
  extern __shared__ __align__(16) unsigned short lds[];
  unsigned short* As0 = lds;                  // 256*64 shorts = 32 KB
  unsigned short* As1 = lds + 16384;
  unsigned short* Bs0 = lds + 32768;
  unsigned short* Bs1 = lds + 49152;

  const int tid = threadIdx.x;
  const int bm0 = blockIdx.y * 256;
  const int bn0 = blockIdx.x * 256;

  const int wave = tid >> 6, lane = tid & 63;
  const int wr = (wave & 3) * 64;    // wave row offset (0..192)
  const int wc = (wave >> 2) * 128;  // wave col offset (0/128)
  const int lr = lane & 15;
  const int q  = lane >> 4;

  f32x4 acc[4][8];
  const f32x4 zero = {0.f, 0.f, 0.f, 0.f};
#pragma unroll
  for (int mi = 0; mi < 4; ++mi)
#pragma unroll
    for (int ni = 0; ni < 8; ++ni)
      acc[mi][ni] = zero;

  const int srow = tid >> 3;        // 0..63
  const int scol = (tid & 7) * 8;

  const unsigned short* xg = xb + (size_t)(bm0 + srow) * K_DIM + scol;
  const unsigned short* wg = wb + (size_t)(bn0 + srow) * K_DIM + scol;
  unsigned short* lA = lds + tid * 8;            // into As0 (+16384 for As1)
  unsigned short* lB = lds + 32768 + tid * 8;    // into Bs0 (+16384 for Bs1)

  stage_tile(xg, wg, lA, lB, 0);                 // prologue: tile 0 -> buf0

  for (int kt = 0; kt < 32; kt += 2) {
    __syncthreads();  // drains this wave's DMA (tile kt, issued a full
                      // compute-phase ago) + syncs: buf1 free to overwrite
    if (kt + 1 < 32)
      stage_tile(xg, wg, lA + 16384, lB + 16384, (kt + 1) * 64);
    compute_tile(As0, Bs0, wr, wc, lr, q, acc);

    __syncthreads();  // drains tile kt+1 DMA; buf0 free to overwrite
    if (kt + 2 < 32)
      stage_tile(xg, wg, lA, lB, (kt + 2) * 64);
    compute_tile(As1, Bs1, wr, wc, lr, q, acc);
  }

  // Epilogue: bias + clamp + exp(v-10); reduce across 16 lanes (128 cols);
  // one fire-and-forget atomic per row per wave (32 contributions/row total).
  float bv[8];
#pragma unroll
  for (int ni = 0; ni < 8; ++ni)
    bv[ni] = bias[bn0 + wc + ni * 16 + lr];

#pragma unroll
  for (int mi = 0; mi < 4; ++mi) {
#pragma unroll
    for (int reg = 0; reg < 4; ++reg) {
      float s = 0.f;
#pragma unroll
      for (int ni = 0; ni < 8; ++ni) {
        float v = acc[mi][ni][reg] + bv[ni];  // SCALE_FACTOR*2 == 1.0
        v = fminf(fmaxf(v, -10.f), 10.f);
        s += __expf(v - 10.f);
      }
      s += __shfl_xor(s, 1);
      s += __shfl_xor(s, 2);
      s += __shfl_xor(s, 4);
      s += __shfl_xor(s, 8);
      if (lr == 0)
        atomicAdd(&S[bm0 + wr + mi * 16 + q * 4 + reg], s);
    }
  }
}

// ---------------- finalize: lse = 10 + log(S); mish(lse) ----------------
__global__ void __launch_bounds__(256) finalize_kernel(const float* __restrict__ S,
                                                       float* __restrict__ out) {
  int i = blockIdx.x * blockDim.x + threadIdx.x;
  float lse = 10.0f + logf(S[i]);
  float sp = fmaxf(lse, 0.f) + log1pf(expf(-fabsf(lse)));  // stable softplus
  out[i] = lse * tanhf(sp);
}

extern "C" void kernel_launch(void* const* d_in, const int* in_sizes, int n_in,
                              void* d_out, int out_size, void* d_ws, size_t ws_size,
                              hipStream_t stream) {
  const float* x = (const float*)d_in[0];   // [4096, 2048]
  const float* W = (const float*)d_in[1];   // [4096, 2048]
  const float* b = (const float*)d_in[2];   // [4096]
  float* out = (float*)d_out;               // [4096]

  char* ws = (char*)d_ws;
  float* S = (float*)ws;                                       // 16 KB
  unsigned short* xb = (unsigned short*)(ws + 16384);          // 16 MB
  unsigned short* wb = (unsigned short*)(ws + 16384 + (size_t)M_DIM * K_DIM * 2);

  const int nG2 = 2 * M_DIM * K_DIM / 8;  // both tensors, 16B granules
  cvt_swz_kernel<<<nG2 / 256, 256, 0, stream>>>(x, W, xb, wb, S);

  // 128 KB dynamic LDS needs the opt-in attribute (idempotent, capture-safe).
  hipFuncSetAttribute((const void*)gemm_lse_kernel,
                      hipFuncAttributeMaxDynamicSharedMemorySize, 131072);
  dim3 grid(N_DIM / 256, M_DIM / 256);  // 16 x 16 = 256 blocks, 1/CU
  gemm_lse_kernel<<<grid, 512, 131072, stream>>>(xb, wb, b, S);

  finalize_kernel<<<M_DIM / 256, 256, 0, stream>>>(S, out);
}